// Round 12
// baseline (6695.581 us; speedup 1.0000x reference)
//
#include <hip/hip_runtime.h>
#include <hip/hip_fp16.h>
#include <math.h>

#define HD 128
#define NGRAPH 64

typedef _Float16 f16x8 __attribute__((ext_vector_type(8)));
typedef _Float16 f16x2 __attribute__((ext_vector_type(2)));
typedef float    f32x4 __attribute__((ext_vector_type(4)));

__device__ __forceinline__ unsigned h2bits(__half2 h){ return *(unsigned*)&h; }

__device__ __forceinline__ float fdot2u(unsigned a, unsigned b, float c){
#if __has_builtin(__builtin_amdgcn_fdot2)
  return __builtin_amdgcn_fdot2(*(f16x2*)&a, *(f16x2*)&b, c, false);
#else
  float2 fa = __half22float2(*(__half2*)&a);
  float2 fb = __half22float2(*(__half2*)&b);
  return c + fa.x*fb.x + fa.y*fb.y;
#endif
}

// ---------------- fused: CSR count (atomic pos) + layer1 projection + wpack + gbounds ----------------
__global__ __launch_bounds__(256) void k_count_setup(
    const int* __restrict__ dst, int* __restrict__ deg, int* __restrict__ epos, int E, int EB,
    const float* __restrict__ X,
    const float* __restrict__ Wq1, const float* __restrict__ bq1,
    const float* __restrict__ Wk1, const float* __restrict__ bk1,
    const float* __restrict__ Wv1, const float* __restrict__ bv1,
    const float* __restrict__ Ws1, const float* __restrict__ bs1,
    const float* __restrict__ Wq, const float* __restrict__ Wk,
    const float* __restrict__ Wv, const float* __restrict__ Ws,
    const int* __restrict__ batch, int* __restrict__ gstart,
    uint4* __restrict__ Wpack,
    unsigned* __restrict__ qh_u, unsigned* __restrict__ kvh_u, unsigned* __restrict__ h_u,
    int N, int L1B){
  int b = blockIdx.x;
  int tid = threadIdx.x;
  if (b < EB){
    int e = b*256 + tid;
    if (e < E) epos[e] = atomicAdd(&deg[dst[e]], 1);
  } else if (b < EB + L1B){
    int idx = (b - EB)*256 + tid;
    if (idx >= N*32) return;
    int n = idx >> 5, s4 = idx & 31, c = s4 << 2;
    float xv = X[n];
    float qv[4], kk[4], vv[4], hv[4];
    #pragma unroll
    for (int i = 0; i < 4; ++i){
      qv[i] = xv*Wq1[c+i] + bq1[c+i];
      kk[i] = xv*Wk1[c+i] + bk1[c+i];
      vv[i] = xv*Wv1[c+i] + bv1[c+i];
      hv[i] = xv*Ws1[c+i] + bs1[c+i];
    }
    uint2 hw;
    hw.x = h2bits(__floats2half2_rn(hv[0], hv[1]));
    hw.y = h2bits(__floats2half2_rn(hv[2], hv[3]));
    *(uint2*)&h_u[(size_t)n*64 + (c >> 1)] = hw;
    uint2 qw;
    qw.x = h2bits(__floats2half2_rn(qv[0], qv[1]));
    qw.y = h2bits(__floats2half2_rn(qv[2], qv[3]));
    *(uint2*)&qh_u[(size_t)n*64 + (c >> 1)] = qw;
    int head = c >> 4, ch = c & 15;
    size_t kbase = (size_t)n*128 + head*16 + (ch >> 1);
    uint2 kw, vw;
    kw.x = h2bits(__floats2half2_rn(kk[0], kk[1]));
    kw.y = h2bits(__floats2half2_rn(kk[2], kk[3]));
    vw.x = h2bits(__floats2half2_rn(vv[0], vv[1]));
    vw.y = h2bits(__floats2half2_rn(vv[2], vv[3]));
    *(uint2*)&kvh_u[kbase]     = kw;
    *(uint2*)&kvh_u[kbase + 8] = vw;
  } else if (b < EB + L1B + 128){
    int idx = (b - EB - L1B)*256 + tid;
    int mi   = idx >> 11;
    int rem  = idx & 2047;
    int lane = rem & 63;
    int tile = rem >> 6;
    int chunk = tile >> 3, nt = tile & 7;
    int l = mi >> 2, ws = mi & 3;
    const float* W = (ws==0?Wq:ws==1?Wk:ws==2?Wv:Ws) + (size_t)l*HD*HD;
    int quad = lane >> 4;
    int n = nt*16 + (lane & 15);
    int k0 = chunk*32 + quad*8;
    __half hs[8];
    #pragma unroll
    for (int j = 0; j < 8; ++j) hs[j] = __float2half(W[(size_t)(k0+j)*HD + n]);
    Wpack[idx] = *(uint4*)hs;
  } else {
    int g = tid;
    if (g > NGRAPH) return;
    int lo = 0, hi = N;
    while (lo < hi){
      int mid = (lo + hi) >> 1;
      if (batch[mid] < g) lo = mid + 1; else hi = mid;
    }
    gstart[g] = lo;
  }
}

// ---------------- scan stage 1 ----------------
__global__ __launch_bounds__(256) void k_scan1(const int* __restrict__ deg, int* __restrict__ rp,
                                               int* __restrict__ bt, int N){
  __shared__ int sm[256];
  int i = blockIdx.x*256 + threadIdx.x;
  int v = (i < N) ? deg[i] : 0;
  sm[threadIdx.x] = v;
  __syncthreads();
  for (int off = 1; off < 256; off <<= 1){
    int t = (threadIdx.x >= (unsigned)off) ? sm[threadIdx.x - off] : 0;
    __syncthreads();
    sm[threadIdx.x] += t;
    __syncthreads();
  }
  if (i < N) rp[i+1] = sm[threadIdx.x];
  if (threadIdx.x == 255) bt[blockIdx.x] = sm[255];
  if (blockIdx.x == 0 && threadIdx.x == 0) rp[0] = 0;
}

// ---------------- scan stage 2 (fused; NB <= 256) ----------------
__global__ __launch_bounds__(256) void k_scan3(int* __restrict__ rp, const int* __restrict__ bt, int N){
  __shared__ int sm[256];
  int b = blockIdx.x, t = threadIdx.x;
  sm[t] = (t < b) ? bt[t] : 0;
  __syncthreads();
  for (int off = 128; off > 0; off >>= 1){
    if (t < off) sm[t] += sm[t + off];
    __syncthreads();
  }
  int offset = sm[0];
  int i = b*256 + t;
  if (i < N) rp[i+1] += offset;
}

__global__ __launch_bounds__(256) void k_scatter(const int* __restrict__ src, const int* __restrict__ dst,
                                                 const int* __restrict__ rp, const int* __restrict__ epos,
                                                 int* __restrict__ srcs, int E){
  int e = blockIdx.x*256 + threadIdx.x;
  if (e < E) srcs[rp[dst[e]] + epos[e]] = src[e];
}

// ---------------- MFMA QKVS GEMM with fused BN on A (stats precomputed in sclbb) ----------------
// grid = (ceil(N/256), 4)
__global__ __launch_bounds__(256) void k_gemm(
    const unsigned* __restrict__ hb_in, const unsigned* __restrict__ xold_u,
    unsigned* __restrict__ xnew_u,
    const uint4* __restrict__ Wpack, const float* __restrict__ sclbb,
    const float* __restrict__ bq, const float* __restrict__ bk,
    const float* __restrict__ bv, const float* __restrict__ bs,
    unsigned* __restrict__ qh_u, unsigned* __restrict__ kvh_u, unsigned* __restrict__ hskip_u,
    int N, int layer, int resid){
  __shared__ uint4 Bs[2048];   // exactly 32 KB
  int wsel = blockIdx.y;
  const uint4* Wm = Wpack + (size_t)(layer*4 + wsel)*2048;
  int tid = threadIdx.x;
  for (int i = tid; i < 2048; i += 256) Bs[i] = Wm[i];

  int w = tid >> 6, lane = tid & 63;
  int l15 = lane & 15, quad = lane >> 4;
  const float* bias = (wsel==0)?bq:(wsel==1)?bk:(wsel==2)?bv:bs;

  __syncthreads();

  for (int rt = 0; rt < 4; ++rt){
    int row0 = blockIdx.x*256 + w*64 + rt*16;
    if (row0 >= N) break;
    int arow = row0 + l15;

    f32x4 acc[8];
    #pragma unroll
    for (int i = 0; i < 8; ++i) acc[i] = (f32x4){0.f,0.f,0.f,0.f};

    #pragma unroll
    for (int chunk = 0; chunk < 4; ++chunk){
      uint4 au = {0u,0u,0u,0u};
      if (arow < N){
        int pbase = chunk*16 + quad*4;
        int cb = chunk*32 + quad*8;
        float4 s0 = *(const float4*)&sclbb[cb];        // wave-uniform per quad, L1-hot
        float4 s1 = *(const float4*)&sclbb[cb + 4];
        float4 c0 = *(const float4*)&sclbb[128 + cb];
        float4 c1 = *(const float4*)&sclbb[128 + cb + 4];
        float scl[8] = {s0.x,s0.y,s0.z,s0.w, s1.x,s1.y,s1.z,s1.w};
        float bbv[8] = {c0.x,c0.y,c0.z,c0.w, c1.x,c1.y,c1.z,c1.w};
        uint4 hv = *(const uint4*)&hb_in[(size_t)arow*64 + pbase];
        unsigned hr[4] = {hv.x, hv.y, hv.z, hv.w};
        unsigned ap[4];
        if (resid){
          uint4 xv = *(const uint4*)&xold_u[(size_t)arow*64 + pbase];
          unsigned xr[4] = {xv.x, xv.y, xv.z, xv.w};
          #pragma unroll
          for (int j = 0; j < 4; ++j){
            float2 hf = __half22float2(*(__half2*)&hr[j]);
            float2 xf = __half22float2(*(__half2*)&xr[j]);
            float o0 = hf.x*scl[2*j]   + bbv[2*j]   + xf.x;
            float o1 = hf.y*scl[2*j+1] + bbv[2*j+1] + xf.y;
            ap[j] = h2bits(__floats2half2_rn(o0, o1));
          }
        } else {
          #pragma unroll
          for (int j = 0; j < 4; ++j){
            float2 hf = __half22float2(*(__half2*)&hr[j]);
            float o0 = hf.x*scl[2*j]   + bbv[2*j];
            float o1 = hf.y*scl[2*j+1] + bbv[2*j+1];
            ap[j] = h2bits(__floats2half2_rn(o0, o1));
          }
        }
        au.x = ap[0]; au.y = ap[1]; au.z = ap[2]; au.w = ap[3];
        if (wsel == 0) *(uint4*)&xnew_u[(size_t)arow*64 + pbase] = au;
      }
      f16x8 a = *(f16x8*)&au;
      #pragma unroll
      for (int nt = 0; nt < 8; ++nt){
        f16x8 bfr = *(const f16x8*)&Bs[(chunk*8 + nt)*64 + lane];
        acc[nt] = __builtin_amdgcn_mfma_f32_16x16x32_f16(a, bfr, acc[nt], 0, 0, 0);
      }
    }

    #pragma unroll
    for (int nt = 0; nt < 8; ++nt){
      int col = nt*16 + l15;
      float b = bias[col];
      #pragma unroll
      for (int reg = 0; reg < 4; ++reg){
        float val = acc[nt][reg] + b;
        float oth = __shfl_xor(val, 1);
        int row = row0 + quad*4 + reg;
        if (!(l15 & 1) && row < N){
          unsigned pk = h2bits(__floats2half2_rn(val, oth));
          if (wsel == 0)       qh_u[(size_t)row*64  + nt*8  + (l15>>1)]      = pk;
          else if (wsel == 1)  kvh_u[(size_t)row*128 + nt*16 + (l15>>1)]     = pk;
          else if (wsel == 2)  kvh_u[(size_t)row*128 + nt*16 + (l15>>1) + 8] = pk;
          else                 hskip_u[(size_t)row*64 + nt*8 + (l15>>1)]     = pk;
        }
      }
    }
  }
}

// ---------------- attention + last-block BN-stats finalize ----------------
__global__ __launch_bounds__(256) void k_attn(
    const uint4* __restrict__ qh4, const uint4* __restrict__ kvh4,
    unsigned* __restrict__ h_u, float* __restrict__ pr2,
    const int* __restrict__ rp, const int* __restrict__ srcs, int N, int layer,
    int* __restrict__ cnt, float* __restrict__ sclbb,
    const float* __restrict__ gamma, const float* __restrict__ beta, float invN){
  __shared__ float ssum[4][128];
  __shared__ float ssq[4][128];
  int tid = threadIdx.x;
  int w = tid >> 6, lane = tid & 63;
  int oct = lane >> 3, hh = lane & 7;
  int n = blockIdx.x*4 + w;
  bool active = (n < N);

  float acc[16];
  #pragma unroll
  for (int i = 0; i < 16; ++i) acc[i] = 0.f;
  float lsum = 0.f;

  if (active){
    uint4 q0 = qh4[(size_t)n*16 + hh*2];
    uint4 q1 = qh4[(size_t)n*16 + hh*2 + 1];
    unsigned qr[8] = {q0.x,q0.y,q0.z,q0.w, q1.x,q1.y,q1.z,q1.w};
    int beg = rp[n], end = rp[n+1];
    int t = beg + oct;
    bool vcur = (t < end);
    uint4 g0, g1, g2, g3;
    if (vcur){
      const uint4* base = kvh4 + (size_t)srcs[t]*32 + hh*4;
      g0 = base[0]; g1 = base[1]; g2 = base[2]; g3 = base[3];
    }
    while (vcur){
      int tn = t + 8;
      bool vn = (tn < end);
      int sn = vn ? srcs[tn] : 0;
      const uint4* nb = kvh4 + (size_t)sn*32 + hh*4;
      uint4 n0 = nb[0], n1 = nb[1], n2 = nb[2], n3 = nb[3];

      unsigned kr[8] = {g0.x,g0.y,g0.z,g0.w, g1.x,g1.y,g1.z,g1.w};
      float pd = 0.f;
      #pragma unroll
      for (int i = 0; i < 8; ++i) pd = fdot2u(kr[i], qr[i], pd);
      float e = __expf(pd * 0.25f);   // no max-subtract: activations BN-bounded
      lsum += e;
      unsigned vr[8] = {g2.x,g2.y,g2.z,g2.w, g3.x,g3.y,g3.z,g3.w};
      #pragma unroll
      for (int i = 0; i < 8; ++i){
        float2 vf = __half22float2(*(__half2*)&vr[i]);
        acc[2*i]   += e*vf.x;
        acc[2*i+1] += e*vf.y;
      }
      g0 = n0; g1 = n1; g2 = n2; g3 = n3;
      t = tn; vcur = vn;
    }
  }

  #pragma unroll
  for (int mask = 8; mask <= 32; mask <<= 1){
    lsum += __shfl_xor(lsum, mask);
    #pragma unroll
    for (int i = 0; i < 16; ++i) acc[i] += __shfl_xor(acc[i], mask);
  }
  float inv = (lsum > 0.f) ? 1.f/lsum : 0.f;

  float out[16];
  #pragma unroll
  for (int i = 0; i < 16; ++i) out[i] = 0.f;
  if (active && oct == 0){
    uint4* hp = (uint4*)(h_u + (size_t)n*64 + hh*8);
    uint4 s0 = hp[0], s1 = hp[1];
    unsigned sr[8] = {s0.x,s0.y,s0.z,s0.w, s1.x,s1.y,s1.z,s1.w};
    #pragma unroll
    for (int i = 0; i < 8; ++i){
      float2 sk = __half22float2(*(__half2*)&sr[i]);
      out[2*i]   = fmaxf(acc[2*i]*inv   + sk.x, 0.f);
      out[2*i+1] = fmaxf(acc[2*i+1]*inv + sk.y, 0.f);
    }
    uint4 w0, w1;
    w0.x = h2bits(__floats2half2_rn(out[0], out[1]));
    w0.y = h2bits(__floats2half2_rn(out[2], out[3]));
    w0.z = h2bits(__floats2half2_rn(out[4], out[5]));
    w0.w = h2bits(__floats2half2_rn(out[6], out[7]));
    w1.x = h2bits(__floats2half2_rn(out[8], out[9]));
    w1.y = h2bits(__floats2half2_rn(out[10], out[11]));
    w1.z = h2bits(__floats2half2_rn(out[12], out[13]));
    w1.w = h2bits(__floats2half2_rn(out[14], out[15]));
    hp[0] = w0; hp[1] = w1;
  }
  if (oct == 0){
    #pragma unroll
    for (int j = 0; j < 16; ++j){
      int pidx = j*8 + hh;
      ssum[w][pidx] = out[j];
      ssq[w][pidx]  = out[j]*out[j];
    }
  }
  __syncthreads();
  float* prow = pr2 + (size_t)(layer & 1)*16384 + (size_t)(blockIdx.x & 63)*256;
  if (tid < 128){
    atomicAdd(&prow[tid], ssum[0][tid]+ssum[1][tid]+ssum[2][tid]+ssum[3][tid]);
  } else {
    int c = tid - 128;
    atomicAdd(&prow[tid], ssq[0][c]+ssq[1][c]+ssq[2][c]+ssq[3][c]);
  }

  // ---- last-block finalize: reduce pr2 -> sclbb, zero parity buffer ----
  __threadfence();
  __shared__ int isLast;
  if (tid == 0){
    int old = atomicAdd(&cnt[layer], 1);
    isLast = (old == (int)gridDim.x - 1);
  }
  __syncthreads();
  if (isLast){
    __threadfence();
    float* pb = pr2 + (size_t)(layer & 1)*16384;
    float s = 0.f;
    #pragma unroll 8
    for (int r = 0; r < 64; ++r)
      s += __hip_atomic_load(&pb[r*256 + tid], __ATOMIC_RELAXED, __HIP_MEMORY_SCOPE_AGENT);
    __shared__ float spos[256];
    spos[tid] = s;
    // zero this parity buffer for attn layer+2 (visible after kernel-end writeback)
    for (int r = 0; r < 64; ++r) pb[r*256 + tid] = 0.f;
    __syncthreads();
    if (tid < 128){
      int c = tid;
      int p = ((c & 15) << 3) | (c >> 4);
      float mu  = spos[p] * invN;
      float var = spos[128 + p] * invN - mu*mu;
      float scl = rsqrtf(var + 1e-5f) * gamma[c];
      sclbb[(layer & 1)*256 + c]       = scl;
      sclbb[(layer & 1)*256 + 128 + c] = beta[c] - mu*scl;
    }
  }
}

// ---------------- pool stage 1 with fused final BN (stats from sclbb) ----------------
__global__ __launch_bounds__(256) void k_pool1(
    const uint4* __restrict__ hb4, const uint4* __restrict__ xold4,
    const int* __restrict__ gstart, float* __restrict__ pp,
    const float* __restrict__ sclbb){
  __shared__ float sm[2048];
  __shared__ float sscl[128], sbb[128];
  int t = threadIdx.x;
  if (t < 128){
    sscl[t] = sclbb[t];
    sbb[t]  = sclbb[128 + t];
  }
  __syncthreads();
  int g = blockIdx.x, chunk = blockIdx.y;
  int tcol = t & 15, trow = t >> 4;
  int start = gstart[g];
  int endr  = gstart[g+1];
  int cb = tcol*8;
  float facc[8];
  #pragma unroll
  for (int j = 0; j < 8; ++j) facc[j] = 0.f;
  for (int r = start + chunk*16 + trow; r < endr; r += 64){
    uint4 hv = hb4[(size_t)r*16 + tcol];
    uint4 xv = xold4[(size_t)r*16 + tcol];
    unsigned hr[4] = {hv.x, hv.y, hv.z, hv.w};
    unsigned xr[4] = {xv.x, xv.y, xv.z, xv.w};
    #pragma unroll
    for (int j = 0; j < 4; ++j){
      float2 hf = __half22float2(*(__half2*)&hr[j]);
      float2 xf = __half22float2(*(__half2*)&xr[j]);
      facc[2*j]   += hf.x*sscl[cb+2*j]   + sbb[cb+2*j]   + xf.x;
      facc[2*j+1] += hf.y*sscl[cb+2*j+1] + sbb[cb+2*j+1] + xf.y;
    }
  }
  #pragma unroll
  for (int j = 0; j < 8; ++j) sm[t*8 + j] = facc[j];
  __syncthreads();
  if (t < 128){
    float s = 0.f;
    #pragma unroll
    for (int r = 0; r < 16; ++r) s += sm[r*128 + t];
    pp[(size_t)(g*4 + chunk)*128 + t] = s;
  }
}

// ---------------- pool stage 2 ----------------
__global__ __launch_bounds__(128) void k_pool2(
    const float* __restrict__ pp, const int* __restrict__ gstart,
    const float* __restrict__ Wr, const float* __restrict__ br,
    float* __restrict__ out){
  __shared__ float sm[128];
  int g = blockIdx.x, c = threadIdx.x;
  float s = 0.f;
  #pragma unroll
  for (int j = 0; j < 4; ++j) s += pp[(size_t)(g*4 + j)*128 + c];
  int cnt = gstart[g+1] - gstart[g];
  float xm = s / fmaxf((float)cnt, 1.f);
  out[NGRAPH + g*HD + c] = xm;
  sm[c] = xm * Wr[c];
  __syncthreads();
  for (int off = 64; off > 0; off >>= 1){
    if (c < off) sm[c] += sm[c + off];
    __syncthreads();
  }
  if (c == 0) out[g] = sm[0] + br[0];
}

extern "C" void kernel_launch(void* const* d_in, const int* in_sizes, int n_in,
                              void* d_out, int out_size, void* d_ws, size_t ws_size,
                              hipStream_t stream){
  const float* X     = (const float*)d_in[0];
  const int*   ei    = (const int*)  d_in[1];
  const int*   batch = (const int*)  d_in[2];
  const float* Wq1 = (const float*)d_in[3];  const float* bq1 = (const float*)d_in[4];
  const float* Wk1 = (const float*)d_in[5];  const float* bk1 = (const float*)d_in[6];
  const float* Wv1 = (const float*)d_in[7];  const float* bv1 = (const float*)d_in[8];
  const float* Ws1 = (const float*)d_in[9];  const float* bs1 = (const float*)d_in[10];
  const float* Wq  = (const float*)d_in[11]; const float* bq  = (const float*)d_in[12];
  const float* Wk  = (const float*)d_in[13]; const float* bk  = (const float*)d_in[14];
  const float* Wv  = (const float*)d_in[15]; const float* bv  = (const float*)d_in[16];
  const float* Ws  = (const float*)d_in[17]; const float* bs  = (const float*)d_in[18];
  const float* bn_g= (const float*)d_in[19]; const float* bn_b= (const float*)d_in[20];
  const float* Wr  = (const float*)d_in[21]; const float* br  = (const float*)d_in[22];

  const int N = in_sizes[0];
  const int E = in_sizes[1] / 2;

  const int* src = ei;
  const int* dst = ei + E;

  char* p = (char*)d_ws;
  auto alloc = [&](size_t bytes) -> void* {
    void* r = (void*)p;
    p += (bytes + 255) & ~(size_t)255;
    return r;
  };
  int*   deg  = (int*)alloc((size_t)N * 4);           // zeroed
  int*   cnt  = (int*)alloc(8 * 4);                   // zeroed
  float* pr2  = (float*)alloc(2 * 64 * 256 * 4);      // zeroed (both parity buffers)
  char* zero_end = p;
  float* sclbb= (float*)alloc(2 * 256 * 4);
  int* rp     = (int*)alloc((size_t)(N + 1) * 4);
  int* bt     = (int*)alloc(256 * 4);
  int* gstart = (int*)alloc((NGRAPH + 1) * 4);
  int* epos   = (int*)alloc((size_t)E * 4);
  int* srcs   = (int*)alloc((size_t)E * 4);
  float* pp   = (float*)alloc((size_t)NGRAPH * 4 * 128 * 4);
  uint4* Wpack= (uint4*)alloc((size_t)16 * 2048 * 16);
  unsigned* qh_u  = (unsigned*)alloc((size_t)N * 64 * 4);
  unsigned* kvh_u = (unsigned*)alloc((size_t)N * 128 * 4);
  unsigned* hb0   = (unsigned*)alloc((size_t)N * 64 * 4);   // h ping-pong
  unsigned* hb1   = (unsigned*)alloc((size_t)N * 64 * 4);
  unsigned* xb0   = (unsigned*)alloc((size_t)N * 64 * 4);   // x ping-pong (fp16 pairs)
  unsigned* xb1   = (unsigned*)alloc((size_t)N * 64 * 4);

  hipMemsetAsync(deg, 0, (size_t)(zero_end - (char*)deg), stream);

  const int NB  = (N + 255) / 256;
  const int EB  = (E + 255) / 256;
  const int L1B = (N * 32 + 255) / 256;
  const int NBLK = (N + 3) / 4;
  const float invN = 1.f / (float)N;

  unsigned* hb[2] = {hb0, hb1};
  unsigned* xb[2] = {xb0, xb1};

  k_count_setup<<<EB + L1B + 129, 256, 0, stream>>>(
      dst, deg, epos, E, EB,
      X, Wq1,bq1, Wk1,bk1, Wv1,bv1, Ws1,bs1,
      Wq, Wk, Wv, Ws, batch, gstart, Wpack, qh_u, kvh_u, hb0, N, L1B);
  k_scan1  <<<NB, 256, 0, stream>>>(deg, rp, bt, N);
  k_scan3  <<<NB, 256, 0, stream>>>(rp, bt, N);
  k_scatter<<<EB, 256, 0, stream>>>(src, dst, rp, epos, srcs, E);

  // layer 1 attention (layer index 0), skip/out in hb0; finalize writes sclbb parity 0
  k_attn<<<NBLK, 256, 0, stream>>>((const uint4*)qh_u, (const uint4*)kvh_u, hb0, pr2, rp, srcs, N, 0,
                                   cnt, sclbb, bn_g, bn_b, invN);

  // layers 2..5: gemm fuses bn_l (A = bn(h'_l) + x_l), attn layer l+1
  for (int l = 0; l < 4; ++l){
    k_gemm<<<dim3((N + 255) / 256, 4), 256, 0, stream>>>(
        hb[l & 1], xb[l & 1], xb[(l + 1) & 1],
        Wpack, sclbb + (size_t)(l & 1)*256,
        bq + (size_t)l*HD, bk + (size_t)l*HD, bv + (size_t)l*HD, bs + (size_t)l*HD,
        qh_u, kvh_u, hb[(l + 1) & 1],
        N, l, (l > 0) ? 1 : 0);
    k_attn<<<NBLK, 256, 0, stream>>>((const uint4*)qh_u, (const uint4*)kvh_u, hb[(l + 1) & 1],
                                     pr2, rp, srcs, N, l + 1,
                                     cnt, sclbb, bn_g + (size_t)(l+1)*HD, bn_b + (size_t)(l+1)*HD, invN);
  }

  // pool (fused bn4: x5 = bn(hb0) + xb0, stats in sclbb parity 0) + head
  k_pool1<<<dim3(NGRAPH, 4), 256, 0, stream>>>(
      (const uint4*)hb0, (const uint4*)xb0, gstart, pp, sclbb);
  k_pool2<<<NGRAPH, 128, 0, stream>>>(pp, gstart, Wr, br, (float*)d_out);
}

// Round 13
// 672.893 us; speedup vs baseline: 9.9504x; 9.9504x over previous
//
#include <hip/hip_runtime.h>
#include <hip/hip_fp16.h>
#include <math.h>

#define HD 128
#define NGRAPH 64

typedef _Float16 f16x8 __attribute__((ext_vector_type(8)));
typedef _Float16 f16x2 __attribute__((ext_vector_type(2)));
typedef float    f32x4 __attribute__((ext_vector_type(4)));

__device__ __forceinline__ unsigned h2bits(__half2 h){ return *(unsigned*)&h; }

__device__ __forceinline__ float fdot2u(unsigned a, unsigned b, float c){
#if __has_builtin(__builtin_amdgcn_fdot2)
  return __builtin_amdgcn_fdot2(*(f16x2*)&a, *(f16x2*)&b, c, false);
#else
  float2 fa = __half22float2(*(__half2*)&a);
  float2 fb = __half22float2(*(__half2*)&b);
  return c + fa.x*fb.x + fa.y*fb.y;
#endif
}

// ---------------- fused: CSR count (atomic pos) + layer1 projection + wpack + gbounds ----------------
__global__ __launch_bounds__(256) void k_count_setup(
    const int* __restrict__ dst, int* __restrict__ deg, int* __restrict__ epos, int E, int EB,
    const float* __restrict__ X,
    const float* __restrict__ Wq1, const float* __restrict__ bq1,
    const float* __restrict__ Wk1, const float* __restrict__ bk1,
    const float* __restrict__ Wv1, const float* __restrict__ bv1,
    const float* __restrict__ Ws1, const float* __restrict__ bs1,
    const float* __restrict__ Wq, const float* __restrict__ Wk,
    const float* __restrict__ Wv, const float* __restrict__ Ws,
    const int* __restrict__ batch, int* __restrict__ gstart,
    uint4* __restrict__ Wpack,
    unsigned* __restrict__ qh_u, unsigned* __restrict__ kvh_u, unsigned* __restrict__ h_u,
    int N, int L1B){
  int b = blockIdx.x;
  int tid = threadIdx.x;
  if (b < EB){
    int e = b*256 + tid;
    if (e < E) epos[e] = atomicAdd(&deg[dst[e]], 1);
  } else if (b < EB + L1B){
    int idx = (b - EB)*256 + tid;
    if (idx >= N*32) return;
    int n = idx >> 5, s4 = idx & 31, c = s4 << 2;
    float xv = X[n];
    float qv[4], kk[4], vv[4], hv[4];
    #pragma unroll
    for (int i = 0; i < 4; ++i){
      qv[i] = xv*Wq1[c+i] + bq1[c+i];
      kk[i] = xv*Wk1[c+i] + bk1[c+i];
      vv[i] = xv*Wv1[c+i] + bv1[c+i];
      hv[i] = xv*Ws1[c+i] + bs1[c+i];
    }
    uint2 hw;
    hw.x = h2bits(__floats2half2_rn(hv[0], hv[1]));
    hw.y = h2bits(__floats2half2_rn(hv[2], hv[3]));
    *(uint2*)&h_u[(size_t)n*64 + (c >> 1)] = hw;
    uint2 qw;
    qw.x = h2bits(__floats2half2_rn(qv[0], qv[1]));
    qw.y = h2bits(__floats2half2_rn(qv[2], qv[3]));
    *(uint2*)&qh_u[(size_t)n*64 + (c >> 1)] = qw;
    int head = c >> 4, ch = c & 15;
    size_t kbase = (size_t)n*128 + head*16 + (ch >> 1);
    uint2 kw, vw;
    kw.x = h2bits(__floats2half2_rn(kk[0], kk[1]));
    kw.y = h2bits(__floats2half2_rn(kk[2], kk[3]));
    vw.x = h2bits(__floats2half2_rn(vv[0], vv[1]));
    vw.y = h2bits(__floats2half2_rn(vv[2], vv[3]));
    *(uint2*)&kvh_u[kbase]     = kw;
    *(uint2*)&kvh_u[kbase + 8] = vw;
  } else if (b < EB + L1B + 128){
    int idx = (b - EB - L1B)*256 + tid;
    int mi   = idx >> 11;
    int rem  = idx & 2047;
    int lane = rem & 63;
    int tile = rem >> 6;
    int chunk = tile >> 3, nt = tile & 7;
    int l = mi >> 2, ws = mi & 3;
    const float* W = (ws==0?Wq:ws==1?Wk:ws==2?Wv:Ws) + (size_t)l*HD*HD;
    int quad = lane >> 4;
    int n = nt*16 + (lane & 15);
    int k0 = chunk*32 + quad*8;
    __half hs[8];
    #pragma unroll
    for (int j = 0; j < 8; ++j) hs[j] = __float2half(W[(size_t)(k0+j)*HD + n]);
    Wpack[idx] = *(uint4*)hs;
  } else {
    int g = tid;
    if (g > NGRAPH) return;
    int lo = 0, hi = N;
    while (lo < hi){
      int mid = (lo + hi) >> 1;
      if (batch[mid] < g) lo = mid + 1; else hi = mid;
    }
    gstart[g] = lo;
  }
}

// ---------------- scan stage 1 ----------------
__global__ __launch_bounds__(256) void k_scan1(const int* __restrict__ deg, int* __restrict__ rp,
                                               int* __restrict__ bt, int N){
  __shared__ int sm[256];
  int i = blockIdx.x*256 + threadIdx.x;
  int v = (i < N) ? deg[i] : 0;
  sm[threadIdx.x] = v;
  __syncthreads();
  for (int off = 1; off < 256; off <<= 1){
    int t = (threadIdx.x >= (unsigned)off) ? sm[threadIdx.x - off] : 0;
    __syncthreads();
    sm[threadIdx.x] += t;
    __syncthreads();
  }
  if (i < N) rp[i+1] = sm[threadIdx.x];
  if (threadIdx.x == 255) bt[blockIdx.x] = sm[255];
  if (blockIdx.x == 0 && threadIdx.x == 0) rp[0] = 0;
}

// ---------------- scan stage 2 (fused; NB <= 256) ----------------
__global__ __launch_bounds__(256) void k_scan3(int* __restrict__ rp, const int* __restrict__ bt, int N){
  __shared__ int sm[256];
  int b = blockIdx.x, t = threadIdx.x;
  sm[t] = (t < b) ? bt[t] : 0;
  __syncthreads();
  for (int off = 128; off > 0; off >>= 1){
    if (t < off) sm[t] += sm[t + off];
    __syncthreads();
  }
  int offset = sm[0];
  int i = b*256 + t;
  if (i < N) rp[i+1] += offset;
}

__global__ __launch_bounds__(256) void k_scatter(const int* __restrict__ src, const int* __restrict__ dst,
                                                 const int* __restrict__ rp, const int* __restrict__ epos,
                                                 int* __restrict__ srcs, int E){
  int e = blockIdx.x*256 + threadIdx.x;
  if (e < E) srcs[rp[dst[e]] + epos[e]] = src[e];
}

// ---------------- BN stats finalize: 1 block; pr2 parity -> sclbb; zero the parity buffer ----------------
__global__ __launch_bounds__(256) void k_stats(
    float* __restrict__ pr2, int layer, float* __restrict__ sclbb,
    const float* __restrict__ gamma, const float* __restrict__ beta, float invN){
  __shared__ float spos[256];
  int t = threadIdx.x;
  float* pb = pr2 + (size_t)(layer & 1)*16384;
  float s = 0.f;
  #pragma unroll 8
  for (int r = 0; r < 64; ++r) s += pb[r*256 + t];
  spos[t] = s;
  // zero this parity buffer for attn layer+2
  #pragma unroll 8
  for (int r = 0; r < 64; ++r) pb[r*256 + t] = 0.f;
  __syncthreads();
  if (t < 128){
    int c = t;
    int p = ((c & 15) << 3) | (c >> 4);   // transposed position holding channel c
    float mu  = spos[p] * invN;
    float var = spos[128 + p] * invN - mu*mu;
    float scl = rsqrtf(var + 1e-5f) * gamma[c];
    sclbb[(layer & 1)*256 + c]       = scl;
    sclbb[(layer & 1)*256 + 128 + c] = beta[c] - mu*scl;
  }
}

// ---------------- MFMA QKVS GEMM with fused BN on A (stats precomputed in sclbb) ----------------
// grid = (ceil(N/256), 4)
__global__ __launch_bounds__(256) void k_gemm(
    const unsigned* __restrict__ hb_in, const unsigned* __restrict__ xold_u,
    unsigned* __restrict__ xnew_u,
    const uint4* __restrict__ Wpack, const float* __restrict__ sclbb,
    const float* __restrict__ bq, const float* __restrict__ bk,
    const float* __restrict__ bv, const float* __restrict__ bs,
    unsigned* __restrict__ qh_u, unsigned* __restrict__ kvh_u, unsigned* __restrict__ hskip_u,
    int N, int layer, int resid){
  __shared__ uint4 Bs[2048];   // exactly 32 KB
  int wsel = blockIdx.y;
  const uint4* Wm = Wpack + (size_t)(layer*4 + wsel)*2048;
  int tid = threadIdx.x;
  for (int i = tid; i < 2048; i += 256) Bs[i] = Wm[i];

  int w = tid >> 6, lane = tid & 63;
  int l15 = lane & 15, quad = lane >> 4;
  const float* bias = (wsel==0)?bq:(wsel==1)?bk:(wsel==2)?bv:bs;

  __syncthreads();

  for (int rt = 0; rt < 4; ++rt){
    int row0 = blockIdx.x*256 + w*64 + rt*16;
    if (row0 >= N) break;
    int arow = row0 + l15;

    f32x4 acc[8];
    #pragma unroll
    for (int i = 0; i < 8; ++i) acc[i] = (f32x4){0.f,0.f,0.f,0.f};

    #pragma unroll
    for (int chunk = 0; chunk < 4; ++chunk){
      uint4 au = {0u,0u,0u,0u};
      if (arow < N){
        int pbase = chunk*16 + quad*4;
        int cb = chunk*32 + quad*8;
        float4 s0 = *(const float4*)&sclbb[cb];
        float4 s1 = *(const float4*)&sclbb[cb + 4];
        float4 c0 = *(const float4*)&sclbb[128 + cb];
        float4 c1 = *(const float4*)&sclbb[128 + cb + 4];
        float scl[8] = {s0.x,s0.y,s0.z,s0.w, s1.x,s1.y,s1.z,s1.w};
        float bbv[8] = {c0.x,c0.y,c0.z,c0.w, c1.x,c1.y,c1.z,c1.w};
        uint4 hv = *(const uint4*)&hb_in[(size_t)arow*64 + pbase];
        unsigned hr[4] = {hv.x, hv.y, hv.z, hv.w};
        unsigned ap[4];
        if (resid){
          uint4 xv = *(const uint4*)&xold_u[(size_t)arow*64 + pbase];
          unsigned xr[4] = {xv.x, xv.y, xv.z, xv.w};
          #pragma unroll
          for (int j = 0; j < 4; ++j){
            float2 hf = __half22float2(*(__half2*)&hr[j]);
            float2 xf = __half22float2(*(__half2*)&xr[j]);
            float o0 = hf.x*scl[2*j]   + bbv[2*j]   + xf.x;
            float o1 = hf.y*scl[2*j+1] + bbv[2*j+1] + xf.y;
            ap[j] = h2bits(__floats2half2_rn(o0, o1));
          }
        } else {
          #pragma unroll
          for (int j = 0; j < 4; ++j){
            float2 hf = __half22float2(*(__half2*)&hr[j]);
            float o0 = hf.x*scl[2*j]   + bbv[2*j];
            float o1 = hf.y*scl[2*j+1] + bbv[2*j+1];
            ap[j] = h2bits(__floats2half2_rn(o0, o1));
          }
        }
        au.x = ap[0]; au.y = ap[1]; au.z = ap[2]; au.w = ap[3];
        if (wsel == 0) *(uint4*)&xnew_u[(size_t)arow*64 + pbase] = au;
      }
      f16x8 a = *(f16x8*)&au;
      #pragma unroll
      for (int nt = 0; nt < 8; ++nt){
        f16x8 bfr = *(const f16x8*)&Bs[(chunk*8 + nt)*64 + lane];
        acc[nt] = __builtin_amdgcn_mfma_f32_16x16x32_f16(a, bfr, acc[nt], 0, 0, 0);
      }
    }

    #pragma unroll
    for (int nt = 0; nt < 8; ++nt){
      int col = nt*16 + l15;
      float b = bias[col];
      #pragma unroll
      for (int reg = 0; reg < 4; ++reg){
        float val = acc[nt][reg] + b;
        float oth = __shfl_xor(val, 1);
        int row = row0 + quad*4 + reg;
        if (!(l15 & 1) && row < N){
          unsigned pk = h2bits(__floats2half2_rn(val, oth));
          if (wsel == 0)       qh_u[(size_t)row*64  + nt*8  + (l15>>1)]      = pk;
          else if (wsel == 1)  kvh_u[(size_t)row*128 + nt*16 + (l15>>1)]     = pk;
          else if (wsel == 2)  kvh_u[(size_t)row*128 + nt*16 + (l15>>1) + 8] = pk;
          else                 hskip_u[(size_t)row*64 + nt*8 + (l15>>1)]     = pk;
        }
      }
    }
  }
}

// ---------------- attention (round-8 body: depth-1 prefetch, no fences) ----------------
__global__ __launch_bounds__(256) void k_attn(
    const uint4* __restrict__ qh4, const uint4* __restrict__ kvh4,
    unsigned* __restrict__ h_u, float* __restrict__ pr2,
    const int* __restrict__ rp, const int* __restrict__ srcs, int N, int layer){
  __shared__ float ssum[4][128];
  __shared__ float ssq[4][128];
  int tid = threadIdx.x;
  int w = tid >> 6, lane = tid & 63;
  int oct = lane >> 3, hh = lane & 7;
  int n = blockIdx.x*4 + w;
  bool active = (n < N);

  float acc[16];
  #pragma unroll
  for (int i = 0; i < 16; ++i) acc[i] = 0.f;
  float lsum = 0.f;

  if (active){
    uint4 q0 = qh4[(size_t)n*16 + hh*2];
    uint4 q1 = qh4[(size_t)n*16 + hh*2 + 1];
    unsigned qr[8] = {q0.x,q0.y,q0.z,q0.w, q1.x,q1.y,q1.z,q1.w};
    int beg = rp[n], end = rp[n+1];
    int t = beg + oct;
    bool vcur = (t < end);
    uint4 g0, g1, g2, g3;
    if (vcur){
      const uint4* base = kvh4 + (size_t)srcs[t]*32 + hh*4;
      g0 = base[0]; g1 = base[1]; g2 = base[2]; g3 = base[3];
    }
    while (vcur){
      int tn = t + 8;
      bool vn = (tn < end);
      int sn = vn ? srcs[tn] : 0;
      const uint4* nb = kvh4 + (size_t)sn*32 + hh*4;
      uint4 n0 = nb[0], n1 = nb[1], n2 = nb[2], n3 = nb[3];

      unsigned kr[8] = {g0.x,g0.y,g0.z,g0.w, g1.x,g1.y,g1.z,g1.w};
      float pd = 0.f;
      #pragma unroll
      for (int i = 0; i < 8; ++i) pd = fdot2u(kr[i], qr[i], pd);
      float e = __expf(pd * 0.25f);   // no max-subtract: activations BN-bounded
      lsum += e;
      unsigned vr[8] = {g2.x,g2.y,g2.z,g2.w, g3.x,g3.y,g3.z,g3.w};
      #pragma unroll
      for (int i = 0; i < 8; ++i){
        float2 vf = __half22float2(*(__half2*)&vr[i]);
        acc[2*i]   += e*vf.x;
        acc[2*i+1] += e*vf.y;
      }
      g0 = n0; g1 = n1; g2 = n2; g3 = n3;
      t = tn; vcur = vn;
    }
  }

  #pragma unroll
  for (int mask = 8; mask <= 32; mask <<= 1){
    lsum += __shfl_xor(lsum, mask);
    #pragma unroll
    for (int i = 0; i < 16; ++i) acc[i] += __shfl_xor(acc[i], mask);
  }
  float inv = (lsum > 0.f) ? 1.f/lsum : 0.f;

  float out[16];
  #pragma unroll
  for (int i = 0; i < 16; ++i) out[i] = 0.f;
  if (active && oct == 0){
    uint4* hp = (uint4*)(h_u + (size_t)n*64 + hh*8);
    uint4 s0 = hp[0], s1 = hp[1];
    unsigned sr[8] = {s0.x,s0.y,s0.z,s0.w, s1.x,s1.y,s1.z,s1.w};
    #pragma unroll
    for (int i = 0; i < 8; ++i){
      float2 sk = __half22float2(*(__half2*)&sr[i]);
      out[2*i]   = fmaxf(acc[2*i]*inv   + sk.x, 0.f);
      out[2*i+1] = fmaxf(acc[2*i+1]*inv + sk.y, 0.f);
    }
    uint4 w0, w1;
    w0.x = h2bits(__floats2half2_rn(out[0], out[1]));
    w0.y = h2bits(__floats2half2_rn(out[2], out[3]));
    w0.z = h2bits(__floats2half2_rn(out[4], out[5]));
    w0.w = h2bits(__floats2half2_rn(out[6], out[7]));
    w1.x = h2bits(__floats2half2_rn(out[8], out[9]));
    w1.y = h2bits(__floats2half2_rn(out[10], out[11]));
    w1.z = h2bits(__floats2half2_rn(out[12], out[13]));
    w1.w = h2bits(__floats2half2_rn(out[14], out[15]));
    hp[0] = w0; hp[1] = w1;
  }
  if (oct == 0){
    #pragma unroll
    for (int j = 0; j < 16; ++j){
      int pidx = j*8 + hh;
      ssum[w][pidx] = out[j];
      ssq[w][pidx]  = out[j]*out[j];
    }
  }
  __syncthreads();
  float* prow = pr2 + (size_t)(layer & 1)*16384 + (size_t)(blockIdx.x & 63)*256;
  if (tid < 128){
    atomicAdd(&prow[tid], ssum[0][tid]+ssum[1][tid]+ssum[2][tid]+ssum[3][tid]);
  } else {
    int c = tid - 128;
    atomicAdd(&prow[tid], ssq[0][c]+ssq[1][c]+ssq[2][c]+ssq[3][c]);
  }
}

// ---------------- pool stage 1 with fused final BN (stats from sclbb) ----------------
__global__ __launch_bounds__(256) void k_pool1(
    const uint4* __restrict__ hb4, const uint4* __restrict__ xold4,
    const int* __restrict__ gstart, float* __restrict__ pp,
    const float* __restrict__ sclbb){
  __shared__ float sm[2048];
  __shared__ float sscl[128], sbb[128];
  int t = threadIdx.x;
  if (t < 128){
    sscl[t] = sclbb[t];
    sbb[t]  = sclbb[128 + t];
  }
  __syncthreads();
  int g = blockIdx.x, chunk = blockIdx.y;
  int tcol = t & 15, trow = t >> 4;
  int start = gstart[g];
  int endr  = gstart[g+1];
  int cb = tcol*8;
  float facc[8];
  #pragma unroll
  for (int j = 0; j < 8; ++j) facc[j] = 0.f;
  for (int r = start + chunk*16 + trow; r < endr; r += 64){
    uint4 hv = hb4[(size_t)r*16 + tcol];
    uint4 xv = xold4[(size_t)r*16 + tcol];
    unsigned hr[4] = {hv.x, hv.y, hv.z, hv.w};
    unsigned xr[4] = {xv.x, xv.y, xv.z, xv.w};
    #pragma unroll
    for (int j = 0; j < 4; ++j){
      float2 hf = __half22float2(*(__half2*)&hr[j]);
      float2 xf = __half22float2(*(__half2*)&xr[j]);
      facc[2*j]   += hf.x*sscl[cb+2*j]   + sbb[cb+2*j]   + xf.x;
      facc[2*j+1] += hf.y*sscl[cb+2*j+1] + sbb[cb+2*j+1] + xf.y;
    }
  }
  #pragma unroll
  for (int j = 0; j < 8; ++j) sm[t*8 + j] = facc[j];
  __syncthreads();
  if (t < 128){
    float s = 0.f;
    #pragma unroll
    for (int r = 0; r < 16; ++r) s += sm[r*128 + t];
    pp[(size_t)(g*4 + chunk)*128 + t] = s;
  }
}

// ---------------- pool stage 2 ----------------
__global__ __launch_bounds__(128) void k_pool2(
    const float* __restrict__ pp, const int* __restrict__ gstart,
    const float* __restrict__ Wr, const float* __restrict__ br,
    float* __restrict__ out){
  __shared__ float sm[128];
  int g = blockIdx.x, c = threadIdx.x;
  float s = 0.f;
  #pragma unroll
  for (int j = 0; j < 4; ++j) s += pp[(size_t)(g*4 + j)*128 + c];
  int cnt = gstart[g+1] - gstart[g];
  float xm = s / fmaxf((float)cnt, 1.f);
  out[NGRAPH + g*HD + c] = xm;
  sm[c] = xm * Wr[c];
  __syncthreads();
  for (int off = 64; off > 0; off >>= 1){
    if (c < off) sm[c] += sm[c + off];
    __syncthreads();
  }
  if (c == 0) out[g] = sm[0] + br[0];
}

extern "C" void kernel_launch(void* const* d_in, const int* in_sizes, int n_in,
                              void* d_out, int out_size, void* d_ws, size_t ws_size,
                              hipStream_t stream){
  const float* X     = (const float*)d_in[0];
  const int*   ei    = (const int*)  d_in[1];
  const int*   batch = (const int*)  d_in[2];
  const float* Wq1 = (const float*)d_in[3];  const float* bq1 = (const float*)d_in[4];
  const float* Wk1 = (const float*)d_in[5];  const float* bk1 = (const float*)d_in[6];
  const float* Wv1 = (const float*)d_in[7];  const float* bv1 = (const float*)d_in[8];
  const float* Ws1 = (const float*)d_in[9];  const float* bs1 = (const float*)d_in[10];
  const float* Wq  = (const float*)d_in[11]; const float* bq  = (const float*)d_in[12];
  const float* Wk  = (const float*)d_in[13]; const float* bk  = (const float*)d_in[14];
  const float* Wv  = (const float*)d_in[15]; const float* bv  = (const float*)d_in[16];
  const float* Ws  = (const float*)d_in[17]; const float* bs  = (const float*)d_in[18];
  const float* bn_g= (const float*)d_in[19]; const float* bn_b= (const float*)d_in[20];
  const float* Wr  = (const float*)d_in[21]; const float* br  = (const float*)d_in[22];

  const int N = in_sizes[0];
  const int E = in_sizes[1] / 2;

  const int* src = ei;
  const int* dst = ei + E;

  char* p = (char*)d_ws;
  auto alloc = [&](size_t bytes) -> void* {
    void* r = (void*)p;
    p += (bytes + 255) & ~(size_t)255;
    return r;
  };
  int*   deg  = (int*)alloc((size_t)N * 4);           // zeroed
  float* pr2  = (float*)alloc(2 * 64 * 256 * 4);      // zeroed (both parity buffers)
  char* zero_end = p;
  float* sclbb= (float*)alloc(2 * 256 * 4);
  int* rp     = (int*)alloc((size_t)(N + 1) * 4);
  int* bt     = (int*)alloc(256 * 4);
  int* gstart = (int*)alloc((NGRAPH + 1) * 4);
  int* epos   = (int*)alloc((size_t)E * 4);
  int* srcs   = (int*)alloc((size_t)E * 4);
  float* pp   = (float*)alloc((size_t)NGRAPH * 4 * 128 * 4);
  uint4* Wpack= (uint4*)alloc((size_t)16 * 2048 * 16);
  unsigned* qh_u  = (unsigned*)alloc((size_t)N * 64 * 4);
  unsigned* kvh_u = (unsigned*)alloc((size_t)N * 128 * 4);
  unsigned* hb0   = (unsigned*)alloc((size_t)N * 64 * 4);   // h ping-pong
  unsigned* hb1   = (unsigned*)alloc((size_t)N * 64 * 4);
  unsigned* xb0   = (unsigned*)alloc((size_t)N * 64 * 4);   // x ping-pong (fp16 pairs)
  unsigned* xb1   = (unsigned*)alloc((size_t)N * 64 * 4);

  hipMemsetAsync(deg, 0, (size_t)(zero_end - (char*)deg), stream);

  const int NB  = (N + 255) / 256;
  const int EB  = (E + 255) / 256;
  const int L1B = (N * 32 + 255) / 256;
  const int NBLK = (N + 3) / 4;
  const float invN = 1.f / (float)N;

  unsigned* hb[2] = {hb0, hb1};
  unsigned* xb[2] = {xb0, xb1};

  k_count_setup<<<EB + L1B + 129, 256, 0, stream>>>(
      dst, deg, epos, E, EB,
      X, Wq1,bq1, Wk1,bk1, Wv1,bv1, Ws1,bs1,
      Wq, Wk, Wv, Ws, batch, gstart, Wpack, qh_u, kvh_u, hb0, N, L1B);
  k_scan1  <<<NB, 256, 0, stream>>>(deg, rp, bt, N);
  k_scan3  <<<NB, 256, 0, stream>>>(rp, bt, N);
  k_scatter<<<EB, 256, 0, stream>>>(src, dst, rp, epos, srcs, E);

  // layer 1 attention (layer index 0), skip/out in hb0
  k_attn <<<NBLK, 256, 0, stream>>>((const uint4*)qh_u, (const uint4*)kvh_u, hb0, pr2, rp, srcs, N, 0);
  k_stats<<<1, 256, 0, stream>>>(pr2, 0, sclbb, bn_g, bn_b, invN);

  // layers 2..5: gemm fuses bn_l (A = bn(h'_l) + x_l), attn layer l+1, stats l+1
  for (int l = 0; l < 4; ++l){
    k_gemm<<<dim3((N + 255) / 256, 4), 256, 0, stream>>>(
        hb[l & 1], xb[l & 1], xb[(l + 1) & 1],
        Wpack, sclbb + (size_t)(l & 1)*256,
        bq + (size_t)l*HD, bk + (size_t)l*HD, bv + (size_t)l*HD, bs + (size_t)l*HD,
        qh_u, kvh_u, hb[(l + 1) & 1],
        N, l, (l > 0) ? 1 : 0);
    k_attn <<<NBLK, 256, 0, stream>>>((const uint4*)qh_u, (const uint4*)kvh_u, hb[(l + 1) & 1],
                                      pr2, rp, srcs, N, l + 1);
    k_stats<<<1, 256, 0, stream>>>(pr2, l + 1, sclbb,
                                   bn_g + (size_t)(l+1)*HD, bn_b + (size_t)(l+1)*HD, invN);
  }

  // pool (fused bn4: x5 = bn(hb0) + xb0, stats in sclbb parity 0) + head
  k_pool1<<<dim3(NGRAPH, 4), 256, 0, stream>>>(
      (const uint4*)hb0, (const uint4*)xb0, gstart, pp, sclbb);
  k_pool2<<<NGRAPH, 128, 0, stream>>>(pp, gstart, Wr, br, (float*)d_out);
}

// Round 14
// 611.331 us; speedup vs baseline: 10.9525x; 1.1007x over previous
//
#include <hip/hip_runtime.h>
#include <hip/hip_fp16.h>
#include <math.h>

#define HD 128
#define NGRAPH 64

typedef _Float16 f16x8 __attribute__((ext_vector_type(8)));
typedef _Float16 f16x2 __attribute__((ext_vector_type(2)));
typedef float    f32x4 __attribute__((ext_vector_type(4)));

__device__ __forceinline__ unsigned h2bits(__half2 h){ return *(unsigned*)&h; }

__device__ __forceinline__ float fdot2u(unsigned a, unsigned b, float c){
#if __has_builtin(__builtin_amdgcn_fdot2)
  return __builtin_amdgcn_fdot2(*(f16x2*)&a, *(f16x2*)&b, c, false);
#else
  float2 fa = __half22float2(*(__half2*)&a);
  float2 fb = __half22float2(*(__half2*)&b);
  return c + fa.x*fb.x + fa.y*fb.y;
#endif
}

// ---------------- fused: CSR count (atomic pos) + layer1 projection + wpack + gbounds ----------------
__global__ __launch_bounds__(256) void k_count_setup(
    const int* __restrict__ dst, int* __restrict__ deg, int* __restrict__ epos, int E, int EB,
    const float* __restrict__ X,
    const float* __restrict__ Wq1, const float* __restrict__ bq1,
    const float* __restrict__ Wk1, const float* __restrict__ bk1,
    const float* __restrict__ Wv1, const float* __restrict__ bv1,
    const float* __restrict__ Ws1, const float* __restrict__ bs1,
    const float* __restrict__ Wq, const float* __restrict__ Wk,
    const float* __restrict__ Wv, const float* __restrict__ Ws,
    const int* __restrict__ batch, int* __restrict__ gstart,
    uint4* __restrict__ Wpack,
    unsigned* __restrict__ qh_u, unsigned* __restrict__ kvh_u, unsigned* __restrict__ h_u,
    int N, int L1B){
  int b = blockIdx.x;
  int tid = threadIdx.x;
  if (b < EB){
    int e = b*256 + tid;
    if (e < E) epos[e] = atomicAdd(&deg[dst[e]], 1);
  } else if (b < EB + L1B){
    int idx = (b - EB)*256 + tid;
    if (idx >= N*32) return;
    int n = idx >> 5, s4 = idx & 31, c = s4 << 2;
    float xv = X[n];
    float qv[4], kk[4], vv[4], hv[4];
    #pragma unroll
    for (int i = 0; i < 4; ++i){
      qv[i] = xv*Wq1[c+i] + bq1[c+i];
      kk[i] = xv*Wk1[c+i] + bk1[c+i];
      vv[i] = xv*Wv1[c+i] + bv1[c+i];
      hv[i] = xv*Ws1[c+i] + bs1[c+i];
    }
    uint2 hw;
    hw.x = h2bits(__floats2half2_rn(hv[0], hv[1]));
    hw.y = h2bits(__floats2half2_rn(hv[2], hv[3]));
    *(uint2*)&h_u[(size_t)n*64 + (c >> 1)] = hw;
    uint2 qw;
    qw.x = h2bits(__floats2half2_rn(qv[0], qv[1]));
    qw.y = h2bits(__floats2half2_rn(qv[2], qv[3]));
    *(uint2*)&qh_u[(size_t)n*64 + (c >> 1)] = qw;
    int head = c >> 4, ch = c & 15;
    size_t kbase = (size_t)n*128 + head*16 + (ch >> 1);
    uint2 kw, vw;
    kw.x = h2bits(__floats2half2_rn(kk[0], kk[1]));
    kw.y = h2bits(__floats2half2_rn(kk[2], kk[3]));
    vw.x = h2bits(__floats2half2_rn(vv[0], vv[1]));
    vw.y = h2bits(__floats2half2_rn(vv[2], vv[3]));
    *(uint2*)&kvh_u[kbase]     = kw;
    *(uint2*)&kvh_u[kbase + 8] = vw;
  } else if (b < EB + L1B + 128){
    int idx = (b - EB - L1B)*256 + tid;
    int mi   = idx >> 11;
    int rem  = idx & 2047;
    int lane = rem & 63;
    int tile = rem >> 6;
    int chunk = tile >> 3, nt = tile & 7;
    int l = mi >> 2, ws = mi & 3;
    const float* W = (ws==0?Wq:ws==1?Wk:ws==2?Wv:Ws) + (size_t)l*HD*HD;
    int quad = lane >> 4;
    int n = nt*16 + (lane & 15);
    int k0 = chunk*32 + quad*8;
    __half hs[8];
    #pragma unroll
    for (int j = 0; j < 8; ++j) hs[j] = __float2half(W[(size_t)(k0+j)*HD + n]);
    Wpack[idx] = *(uint4*)hs;
  } else {
    int g = tid;
    if (g > NGRAPH) return;
    int lo = 0, hi = N;
    while (lo < hi){
      int mid = (lo + hi) >> 1;
      if (batch[mid] < g) lo = mid + 1; else hi = mid;
    }
    gstart[g] = lo;
  }
}

// ---------------- scan stage 1 ----------------
__global__ __launch_bounds__(256) void k_scan1(const int* __restrict__ deg, int* __restrict__ rp,
                                               int* __restrict__ bt, int N){
  __shared__ int sm[256];
  int i = blockIdx.x*256 + threadIdx.x;
  int v = (i < N) ? deg[i] : 0;
  sm[threadIdx.x] = v;
  __syncthreads();
  for (int off = 1; off < 256; off <<= 1){
    int t = (threadIdx.x >= (unsigned)off) ? sm[threadIdx.x - off] : 0;
    __syncthreads();
    sm[threadIdx.x] += t;
    __syncthreads();
  }
  if (i < N) rp[i+1] = sm[threadIdx.x];
  if (threadIdx.x == 255) bt[blockIdx.x] = sm[255];
  if (blockIdx.x == 0 && threadIdx.x == 0) rp[0] = 0;
}

// ---------------- scan stage 2 (fused; NB <= 256) ----------------
__global__ __launch_bounds__(256) void k_scan3(int* __restrict__ rp, const int* __restrict__ bt, int N){
  __shared__ int sm[256];
  int b = blockIdx.x, t = threadIdx.x;
  sm[t] = (t < b) ? bt[t] : 0;
  __syncthreads();
  for (int off = 128; off > 0; off >>= 1){
    if (t < off) sm[t] += sm[t + off];
    __syncthreads();
  }
  int offset = sm[0];
  int i = b*256 + t;
  if (i < N) rp[i+1] += offset;
}

__global__ __launch_bounds__(256) void k_scatter(const int* __restrict__ src, const int* __restrict__ dst,
                                                 const int* __restrict__ rp, const int* __restrict__ epos,
                                                 int* __restrict__ srcs, int E){
  int e = blockIdx.x*256 + threadIdx.x;
  if (e < E) srcs[rp[dst[e]] + epos[e]] = src[e];
}

// ---------------- BN stats finalize: 1 block; pr2 parity -> sclbb; zero the parity buffer ----------------
__global__ __launch_bounds__(256) void k_stats(
    float* __restrict__ pr2, int layer, float* __restrict__ sclbb,
    const float* __restrict__ gamma, const float* __restrict__ beta, float invN){
  __shared__ float spos[256];
  int t = threadIdx.x;
  float* pb = pr2 + (size_t)(layer & 1)*16384;
  float s = 0.f;
  #pragma unroll 8
  for (int r = 0; r < 64; ++r) s += pb[r*256 + t];
  spos[t] = s;
  #pragma unroll 8
  for (int r = 0; r < 64; ++r) pb[r*256 + t] = 0.f;
  __syncthreads();
  if (t < 128){
    int c = t;
    int p = ((c & 15) << 3) | (c >> 4);
    float mu  = spos[p] * invN;
    float var = spos[128 + p] * invN - mu*mu;
    float scl = rsqrtf(var + 1e-5f) * gamma[c];
    sclbb[(layer & 1)*256 + c]       = scl;
    sclbb[(layer & 1)*256 + 128 + c] = beta[c] - mu*scl;
  }
}

// ---------------- merged 4-matrix MFMA GEMM: BN-normalized A built ONCE into regs ----------------
// grid = ceil(N/64); block = 4 waves, wave w -> rows [64b + 16w, +16)
__global__ __launch_bounds__(256) void k_gemm(
    const unsigned* __restrict__ hb_in, const unsigned* __restrict__ xold_u,
    unsigned* __restrict__ xnew_u,
    const uint4* __restrict__ Wpack, const float* __restrict__ sclbb,
    const float* __restrict__ bq, const float* __restrict__ bk,
    const float* __restrict__ bv, const float* __restrict__ bs,
    unsigned* __restrict__ qh_u, unsigned* __restrict__ kvh_u, unsigned* __restrict__ hskip_u,
    int N, int layer, int resid){
  __shared__ uint4 Bs[2048];   // exactly 32 KB, reused per matrix
  int tid = threadIdx.x;
  int w = tid >> 6, lane = tid & 63;
  int l15 = lane & 15, quad = lane >> 4;
  int row0 = blockIdx.x*64 + w*16;
  int arow = row0 + l15;

  const uint4* Wl = Wpack + (size_t)layer*4*2048;

  // stage ws=0 weights while building A
  for (int i = tid; i < 2048; i += 256) Bs[i] = Wl[i];

  // build BN(+residual) A fragments once; write xnew once
  uint4 Areg[4];
  #pragma unroll
  for (int chunk = 0; chunk < 4; ++chunk){
    uint4 au = {0u,0u,0u,0u};
    if (arow < N){
      int pbase = chunk*16 + quad*4;
      int cb = chunk*32 + quad*8;
      float4 s0 = *(const float4*)&sclbb[cb];
      float4 s1 = *(const float4*)&sclbb[cb + 4];
      float4 c0 = *(const float4*)&sclbb[128 + cb];
      float4 c1 = *(const float4*)&sclbb[128 + cb + 4];
      float scl[8] = {s0.x,s0.y,s0.z,s0.w, s1.x,s1.y,s1.z,s1.w};
      float bbv[8] = {c0.x,c0.y,c0.z,c0.w, c1.x,c1.y,c1.z,c1.w};
      uint4 hv = *(const uint4*)&hb_in[(size_t)arow*64 + pbase];
      unsigned hr[4] = {hv.x, hv.y, hv.z, hv.w};
      unsigned ap[4];
      if (resid){
        uint4 xv = *(const uint4*)&xold_u[(size_t)arow*64 + pbase];
        unsigned xr[4] = {xv.x, xv.y, xv.z, xv.w};
        #pragma unroll
        for (int j = 0; j < 4; ++j){
          float2 hf = __half22float2(*(__half2*)&hr[j]);
          float2 xf = __half22float2(*(__half2*)&xr[j]);
          float o0 = hf.x*scl[2*j]   + bbv[2*j]   + xf.x;
          float o1 = hf.y*scl[2*j+1] + bbv[2*j+1] + xf.y;
          ap[j] = h2bits(__floats2half2_rn(o0, o1));
        }
      } else {
        #pragma unroll
        for (int j = 0; j < 4; ++j){
          float2 hf = __half22float2(*(__half2*)&hr[j]);
          float o0 = hf.x*scl[2*j]   + bbv[2*j];
          float o1 = hf.y*scl[2*j+1] + bbv[2*j+1];
          ap[j] = h2bits(__floats2half2_rn(o0, o1));
        }
      }
      au.x = ap[0]; au.y = ap[1]; au.z = ap[2]; au.w = ap[3];
      *(uint4*)&xnew_u[(size_t)arow*64 + pbase] = au;
    }
    Areg[chunk] = au;
  }

  #pragma unroll
  for (int ws = 0; ws < 4; ++ws){
    if (ws > 0){
      __syncthreads();   // prior matrix's MFMA reads done
      const uint4* Wm = Wl + (size_t)ws*2048;
      for (int i = tid; i < 2048; i += 256) Bs[i] = Wm[i];
    }
    __syncthreads();

    f32x4 acc[8];
    #pragma unroll
    for (int i = 0; i < 8; ++i) acc[i] = (f32x4){0.f,0.f,0.f,0.f};

    #pragma unroll
    for (int chunk = 0; chunk < 4; ++chunk){
      f16x8 a = *(f16x8*)&Areg[chunk];
      #pragma unroll
      for (int nt = 0; nt < 8; ++nt){
        f16x8 bfr = *(const f16x8*)&Bs[(chunk*8 + nt)*64 + lane];
        acc[nt] = __builtin_amdgcn_mfma_f32_16x16x32_f16(a, bfr, acc[nt], 0, 0, 0);
      }
    }

    const float* bias = (ws==0)?bq:(ws==1)?bk:(ws==2)?bv:bs;
    #pragma unroll
    for (int nt = 0; nt < 8; ++nt){
      int col = nt*16 + l15;
      float b = bias[col];
      #pragma unroll
      for (int reg = 0; reg < 4; ++reg){
        float val = acc[nt][reg] + b;
        float oth = __shfl_xor(val, 1);
        int row = row0 + quad*4 + reg;
        if (!(l15 & 1) && row < N){
          unsigned pk = h2bits(__floats2half2_rn(val, oth));
          if (ws == 0)       qh_u[(size_t)row*64  + nt*8  + (l15>>1)]      = pk;
          else if (ws == 1)  kvh_u[(size_t)row*128 + nt*16 + (l15>>1)]     = pk;
          else if (ws == 2)  kvh_u[(size_t)row*128 + nt*16 + (l15>>1) + 8] = pk;
          else               hskip_u[(size_t)row*64 + nt*8 + (l15>>1)]     = pk;
        }
      }
    }
  }
}

// ---------------- attention (round-8 body: depth-1 prefetch, no fences) ----------------
__global__ __launch_bounds__(256) void k_attn(
    const uint4* __restrict__ qh4, const uint4* __restrict__ kvh4,
    unsigned* __restrict__ h_u, float* __restrict__ pr2,
    const int* __restrict__ rp, const int* __restrict__ srcs, int N, int layer){
  __shared__ float ssum[4][128];
  __shared__ float ssq[4][128];
  int tid = threadIdx.x;
  int w = tid >> 6, lane = tid & 63;
  int oct = lane >> 3, hh = lane & 7;
  int n = blockIdx.x*4 + w;
  bool active = (n < N);

  float acc[16];
  #pragma unroll
  for (int i = 0; i < 16; ++i) acc[i] = 0.f;
  float lsum = 0.f;

  if (active){
    uint4 q0 = qh4[(size_t)n*16 + hh*2];
    uint4 q1 = qh4[(size_t)n*16 + hh*2 + 1];
    unsigned qr[8] = {q0.x,q0.y,q0.z,q0.w, q1.x,q1.y,q1.z,q1.w};
    int beg = rp[n], end = rp[n+1];
    int t = beg + oct;
    bool vcur = (t < end);
    uint4 g0, g1, g2, g3;
    if (vcur){
      const uint4* base = kvh4 + (size_t)srcs[t]*32 + hh*4;
      g0 = base[0]; g1 = base[1]; g2 = base[2]; g3 = base[3];
    }
    while (vcur){
      int tn = t + 8;
      bool vn = (tn < end);
      int sn = vn ? srcs[tn] : 0;
      const uint4* nb = kvh4 + (size_t)sn*32 + hh*4;
      uint4 n0 = nb[0], n1 = nb[1], n2 = nb[2], n3 = nb[3];

      unsigned kr[8] = {g0.x,g0.y,g0.z,g0.w, g1.x,g1.y,g1.z,g1.w};
      float pd = 0.f;
      #pragma unroll
      for (int i = 0; i < 8; ++i) pd = fdot2u(kr[i], qr[i], pd);
      float e = __expf(pd * 0.25f);   // no max-subtract: activations BN-bounded
      lsum += e;
      unsigned vr[8] = {g2.x,g2.y,g2.z,g2.w, g3.x,g3.y,g3.z,g3.w};
      #pragma unroll
      for (int i = 0; i < 8; ++i){
        float2 vf = __half22float2(*(__half2*)&vr[i]);
        acc[2*i]   += e*vf.x;
        acc[2*i+1] += e*vf.y;
      }
      g0 = n0; g1 = n1; g2 = n2; g3 = n3;
      t = tn; vcur = vn;
    }
  }

  #pragma unroll
  for (int mask = 8; mask <= 32; mask <<= 1){
    lsum += __shfl_xor(lsum, mask);
    #pragma unroll
    for (int i = 0; i < 16; ++i) acc[i] += __shfl_xor(acc[i], mask);
  }
  float inv = (lsum > 0.f) ? 1.f/lsum : 0.f;

  float out[16];
  #pragma unroll
  for (int i = 0; i < 16; ++i) out[i] = 0.f;
  if (active && oct == 0){
    uint4* hp = (uint4*)(h_u + (size_t)n*64 + hh*8);
    uint4 s0 = hp[0], s1 = hp[1];
    unsigned sr[8] = {s0.x,s0.y,s0.z,s0.w, s1.x,s1.y,s1.z,s1.w};
    #pragma unroll
    for (int i = 0; i < 8; ++i){
      float2 sk = __half22float2(*(__half2*)&sr[i]);
      out[2*i]   = fmaxf(acc[2*i]*inv   + sk.x, 0.f);
      out[2*i+1] = fmaxf(acc[2*i+1]*inv + sk.y, 0.f);
    }
    uint4 w0, w1;
    w0.x = h2bits(__floats2half2_rn(out[0], out[1]));
    w0.y = h2bits(__floats2half2_rn(out[2], out[3]));
    w0.z = h2bits(__floats2half2_rn(out[4], out[5]));
    w0.w = h2bits(__floats2half2_rn(out[6], out[7]));
    w1.x = h2bits(__floats2half2_rn(out[8], out[9]));
    w1.y = h2bits(__floats2half2_rn(out[10], out[11]));
    w1.z = h2bits(__floats2half2_rn(out[12], out[13]));
    w1.w = h2bits(__floats2half2_rn(out[14], out[15]));
    hp[0] = w0; hp[1] = w1;
  }
  if (oct == 0){
    #pragma unroll
    for (int j = 0; j < 16; ++j){
      int pidx = j*8 + hh;
      ssum[w][pidx] = out[j];
      ssq[w][pidx]  = out[j]*out[j];
    }
  }
  __syncthreads();
  float* prow = pr2 + (size_t)(layer & 1)*16384 + (size_t)(blockIdx.x & 63)*256;
  if (tid < 128){
    atomicAdd(&prow[tid], ssum[0][tid]+ssum[1][tid]+ssum[2][tid]+ssum[3][tid]);
  } else {
    int c = tid - 128;
    atomicAdd(&prow[tid], ssq[0][c]+ssq[1][c]+ssq[2][c]+ssq[3][c]);
  }
}

// ---------------- pool stage 1 with fused final BN (stats from sclbb) ----------------
__global__ __launch_bounds__(256) void k_pool1(
    const uint4* __restrict__ hb4, const uint4* __restrict__ xold4,
    const int* __restrict__ gstart, float* __restrict__ pp,
    const float* __restrict__ sclbb){
  __shared__ float sm[2048];
  __shared__ float sscl[128], sbb[128];
  int t = threadIdx.x;
  if (t < 128){
    sscl[t] = sclbb[t];
    sbb[t]  = sclbb[128 + t];
  }
  __syncthreads();
  int g = blockIdx.x, chunk = blockIdx.y;
  int tcol = t & 15, trow = t >> 4;
  int start = gstart[g];
  int endr  = gstart[g+1];
  int cb = tcol*8;
  float facc[8];
  #pragma unroll
  for (int j = 0; j < 8; ++j) facc[j] = 0.f;
  for (int r = start + chunk*16 + trow; r < endr; r += 64){
    uint4 hv = hb4[(size_t)r*16 + tcol];
    uint4 xv = xold4[(size_t)r*16 + tcol];
    unsigned hr[4] = {hv.x, hv.y, hv.z, hv.w};
    unsigned xr[4] = {xv.x, xv.y, xv.z, xv.w};
    #pragma unroll
    for (int j = 0; j < 4; ++j){
      float2 hf = __half22float2(*(__half2*)&hr[j]);
      float2 xf = __half22float2(*(__half2*)&xr[j]);
      facc[2*j]   += hf.x*sscl[cb+2*j]   + sbb[cb+2*j]   + xf.x;
      facc[2*j+1] += hf.y*sscl[cb+2*j+1] + sbb[cb+2*j+1] + xf.y;
    }
  }
  #pragma unroll
  for (int j = 0; j < 8; ++j) sm[t*8 + j] = facc[j];
  __syncthreads();
  if (t < 128){
    float s = 0.f;
    #pragma unroll
    for (int r = 0; r < 16; ++r) s += sm[r*128 + t];
    pp[(size_t)(g*4 + chunk)*128 + t] = s;
  }
}

// ---------------- pool stage 2 ----------------
__global__ __launch_bounds__(128) void k_pool2(
    const float* __restrict__ pp, const int* __restrict__ gstart,
    const float* __restrict__ Wr, const float* __restrict__ br,
    float* __restrict__ out){
  __shared__ float sm[128];
  int g = blockIdx.x, c = threadIdx.x;
  float s = 0.f;
  #pragma unroll
  for (int j = 0; j < 4; ++j) s += pp[(size_t)(g*4 + j)*128 + c];
  int cnt = gstart[g+1] - gstart[g];
  float xm = s / fmaxf((float)cnt, 1.f);
  out[NGRAPH + g*HD + c] = xm;
  sm[c] = xm * Wr[c];
  __syncthreads();
  for (int off = 64; off > 0; off >>= 1){
    if (c < off) sm[c] += sm[c + off];
    __syncthreads();
  }
  if (c == 0) out[g] = sm[0] + br[0];
}

extern "C" void kernel_launch(void* const* d_in, const int* in_sizes, int n_in,
                              void* d_out, int out_size, void* d_ws, size_t ws_size,
                              hipStream_t stream){
  const float* X     = (const float*)d_in[0];
  const int*   ei    = (const int*)  d_in[1];
  const int*   batch = (const int*)  d_in[2];
  const float* Wq1 = (const float*)d_in[3];  const float* bq1 = (const float*)d_in[4];
  const float* Wk1 = (const float*)d_in[5];  const float* bk1 = (const float*)d_in[6];
  const float* Wv1 = (const float*)d_in[7];  const float* bv1 = (const float*)d_in[8];
  const float* Ws1 = (const float*)d_in[9];  const float* bs1 = (const float*)d_in[10];
  const float* Wq  = (const float*)d_in[11]; const float* bq  = (const float*)d_in[12];
  const float* Wk  = (const float*)d_in[13]; const float* bk  = (const float*)d_in[14];
  const float* Wv  = (const float*)d_in[15]; const float* bv  = (const float*)d_in[16];
  const float* Ws  = (const float*)d_in[17]; const float* bs  = (const float*)d_in[18];
  const float* bn_g= (const float*)d_in[19]; const float* bn_b= (const float*)d_in[20];
  const float* Wr  = (const float*)d_in[21]; const float* br  = (const float*)d_in[22];

  const int N = in_sizes[0];
  const int E = in_sizes[1] / 2;

  const int* src = ei;
  const int* dst = ei + E;

  char* p = (char*)d_ws;
  auto alloc = [&](size_t bytes) -> void* {
    void* r = (void*)p;
    p += (bytes + 255) & ~(size_t)255;
    return r;
  };
  int*   deg  = (int*)alloc((size_t)N * 4);           // zeroed
  float* pr2  = (float*)alloc(2 * 64 * 256 * 4);      // zeroed (both parity buffers)
  char* zero_end = p;
  float* sclbb= (float*)alloc(2 * 256 * 4);
  int* rp     = (int*)alloc((size_t)(N + 1) * 4);
  int* bt     = (int*)alloc(256 * 4);
  int* gstart = (int*)alloc((NGRAPH + 1) * 4);
  int* epos   = (int*)alloc((size_t)E * 4);
  int* srcs   = (int*)alloc((size_t)E * 4);
  float* pp   = (float*)alloc((size_t)NGRAPH * 4 * 128 * 4);
  uint4* Wpack= (uint4*)alloc((size_t)16 * 2048 * 16);
  unsigned* qh_u  = (unsigned*)alloc((size_t)N * 64 * 4);
  unsigned* kvh_u = (unsigned*)alloc((size_t)N * 128 * 4);
  unsigned* hb0   = (unsigned*)alloc((size_t)N * 64 * 4);   // h ping-pong
  unsigned* hb1   = (unsigned*)alloc((size_t)N * 64 * 4);
  unsigned* xb0   = (unsigned*)alloc((size_t)N * 64 * 4);   // x ping-pong (fp16 pairs)
  unsigned* xb1   = (unsigned*)alloc((size_t)N * 64 * 4);

  hipMemsetAsync(deg, 0, (size_t)(zero_end - (char*)deg), stream);

  const int NB  = (N + 255) / 256;
  const int EB  = (E + 255) / 256;
  const int L1B = (N * 32 + 255) / 256;
  const int NBLK = (N + 3) / 4;
  const float invN = 1.f / (float)N;

  unsigned* hb[2] = {hb0, hb1};
  unsigned* xb[2] = {xb0, xb1};

  k_count_setup<<<EB + L1B + 129, 256, 0, stream>>>(
      dst, deg, epos, E, EB,
      X, Wq1,bq1, Wk1,bk1, Wv1,bv1, Ws1,bs1,
      Wq, Wk, Wv, Ws, batch, gstart, Wpack, qh_u, kvh_u, hb0, N, L1B);
  k_scan1  <<<NB, 256, 0, stream>>>(deg, rp, bt, N);
  k_scan3  <<<NB, 256, 0, stream>>>(rp, bt, N);
  k_scatter<<<EB, 256, 0, stream>>>(src, dst, rp, epos, srcs, E);

  // layer 1 attention (layer index 0), skip/out in hb0
  k_attn <<<NBLK, 256, 0, stream>>>((const uint4*)qh_u, (const uint4*)kvh_u, hb0, pr2, rp, srcs, N, 0);
  k_stats<<<1, 256, 0, stream>>>(pr2, 0, sclbb, bn_g, bn_b, invN);

  // layers 2..5: merged gemm fuses bn_l (A = bn(h'_l) + x_l), attn layer l+1, stats l+1
  for (int l = 0; l < 4; ++l){
    k_gemm<<<(N + 63) / 64, 256, 0, stream>>>(
        hb[l & 1], xb[l & 1], xb[(l + 1) & 1],
        Wpack, sclbb + (size_t)(l & 1)*256,
        bq + (size_t)l*HD, bk + (size_t)l*HD, bv + (size_t)l*HD, bs + (size_t)l*HD,
        qh_u, kvh_u, hb[(l + 1) & 1],
        N, l, (l > 0) ? 1 : 0);
    k_attn <<<NBLK, 256, 0, stream>>>((const uint4*)qh_u, (const uint4*)kvh_u, hb[(l + 1) & 1],
                                      pr2, rp, srcs, N, l + 1);
    k_stats<<<1, 256, 0, stream>>>(pr2, l + 1, sclbb,
                                   bn_g + (size_t)(l+1)*HD, bn_b + (size_t)(l+1)*HD, invN);
  }

  // pool (fused bn4: x5 = bn(hb0) + xb0, stats in sclbb parity 0) + head
  k_pool1<<<dim3(NGRAPH, 4), 256, 0, stream>>>(
      (const uint4*)hb0, (const uint4*)xb0, gstart, pp, sclbb);
  k_pool2<<<NGRAPH, 128, 0, stream>>>(pp, gstart, Wr, br, (float*)d_out);
}